// Round 3
// baseline (2259.524 us; speedup 1.0000x reference)
//
#include <hip/hip_runtime.h>

constexpr int N = 200000;
constexpr int E = 5000000;
constexpr int F = 16;
constexpr int SLICES = 4;
constexpr int SLICE_SZ = N / SLICES;   // 50000, L2-sized h slice (3.2 MB)

// ---- pass 1: degree count + per-edge position (counting-sort prep) ----
__global__ void degpos_kernel(const int* __restrict__ dst, int* __restrict__ cnt,
                              int* __restrict__ pos) {
    int stride = gridDim.x * blockDim.x;
    for (int e = blockIdx.x * blockDim.x + threadIdx.x; e < E; e += stride) {
        int p = atomicAdd(&cnt[dst[e]], 1);
        __builtin_nontemporal_store(p, &pos[e]);
    }
}

// ---- exclusive scan of cnt -> off, 3 kernels ----
__global__ void scanA_kernel(const int* __restrict__ cnt, int* __restrict__ bsum) {
    __shared__ int sm[256];
    int n = blockIdx.x * 256 + threadIdx.x;
    int v = (n < N) ? cnt[n] : 0;
    sm[threadIdx.x] = v; __syncthreads();
    for (int s = 128; s > 0; s >>= 1) {
        if (threadIdx.x < s) sm[threadIdx.x] += sm[threadIdx.x + s];
        __syncthreads();
    }
    if (threadIdx.x == 0) bsum[blockIdx.x] = sm[0];
}

__global__ void scanB_kernel(const int* __restrict__ bsum, int* __restrict__ bpre, int nb) {
    __shared__ int sm[1024];
    int i = threadIdx.x;
    int v = (i < nb) ? bsum[i] : 0;
    sm[i] = v; __syncthreads();
    for (int s = 1; s < 1024; s <<= 1) {
        int t = (i >= s) ? sm[i - s] : 0;
        __syncthreads();
        sm[i] += t;
        __syncthreads();
    }
    if (i < nb) bpre[i] = sm[i] - v;   // exclusive
}

__global__ void scanC_kernel(const int* __restrict__ cnt, const int* __restrict__ bpre,
                             int* __restrict__ off) {
    __shared__ int sm[256];
    int n = blockIdx.x * 256 + threadIdx.x;
    int v = (n < N) ? cnt[n] : 0;
    sm[threadIdx.x] = v; __syncthreads();
    for (int s = 1; s < 256; s <<= 1) {
        int t = (threadIdx.x >= s) ? sm[threadIdx.x - s] : 0;
        __syncthreads();
        sm[threadIdx.x] += t;
        __syncthreads();
    }
    int inc = sm[threadIdx.x];
    int base = bpre[blockIdx.x];
    if (n < N) off[n] = base + inc - v;
    if (n == N - 1) off[N] = base + inc;
}

// ---- pass 2: fill CSR column list (nontemporal scattered 4B stores) ----
__global__ void fill_kernel(const int* __restrict__ src, const int* __restrict__ dst,
                            const int* __restrict__ pos, const int* __restrict__ off,
                            int* __restrict__ col) {
    int stride = gridDim.x * blockDim.x;
    for (int e = blockIdx.x * blockDim.x + threadIdx.x; e < E; e += stride) {
        int idx = off[dst[e]] + pos[e];
        __builtin_nontemporal_store(src[e], &col[idx]);
    }
}

// ---- fused gather + SAGE update (+optional fc1 / fc2+softmax) ----
// block = 256 threads = 16 nodes x 16 feature-lanes; N/16 = 12500 blocks exactly
__global__ __launch_bounds__(256) void layer_kernel(
    const float* __restrict__ hin, float* __restrict__ hout,
    const int* __restrict__ off, const int* __restrict__ col,
    const float* __restrict__ Wl, const float* __restrict__ bl,
    const float* __restrict__ Wr,
    const float* __restrict__ fcW, const float* __restrict__ fcb,
    int mode,                 // 0 = plain, 1 = +fc1+relu, 2 = final (slice8+fc2+relu+softmax)
    float* __restrict__ outp) {
    __shared__ float Mt[16][17], Xt[16][17];
    const int ty = threadIdx.x >> 4;
    const int k  = threadIdx.x & 15;
    const int n  = blockIdx.x * 16 + ty;
    const int o0 = off[n], o1 = off[n + 1];

    float acc = 0.f;
    // neighbor gather in 4 source-range slices: keeps the 3.2MB h-slice L2-resident;
    // col re-reads are L1-hot (per-node list ~100B)
    for (int s = 0; s < SLICES; s++) {
        const int lo = s * SLICE_SZ;
        for (int j = o0; j < o1; j++) {
            int c = col[j];
            if ((unsigned)(c - lo) < (unsigned)SLICE_SZ) acc += hin[c * F + k];
        }
    }
    const float inv = 1.f / fmaxf((float)(o1 - o0), 1.f);
    Mt[ty][k] = acc * inv;
    Xt[ty][k] = hin[n * F + k];
    __syncthreads();

    float a = bl[k];
#pragma unroll
    for (int kk = 0; kk < F; kk++)
        a = fmaf(Mt[ty][kk], Wl[k * F + kk], fmaf(Xt[ty][kk], Wr[k * F + kk], a));
    float o = fmaxf(a, 0.f);   // relu follows every SAGE layer in this graph

    if (mode == 0) { hout[n * F + k] = o; return; }

    __syncthreads();
    Mt[ty][k] = o;
    __syncthreads();

    if (mode == 1) {
        float a2 = fcb[k];
#pragma unroll
        for (int kk = 0; kk < F; kk++) a2 = fmaf(Mt[ty][kk], fcW[k * F + kk], a2);
        hout[n * F + k] = fmaxf(a2, 0.f);
        return;
    }

    // final: slice [:, :8] -> fc2 (8x8) -> relu -> softmax over 8
    if (k < 8) {
        float a2 = fcb[k];
#pragma unroll
        for (int kk = 0; kk < 8; kk++) a2 = fmaf(Mt[ty][kk], fcW[k * 8 + kk], a2);
        float u = fmaxf(a2, 0.f);
        float mx = u;
        mx = fmaxf(mx, __shfl_xor(mx, 1));
        mx = fmaxf(mx, __shfl_xor(mx, 2));
        mx = fmaxf(mx, __shfl_xor(mx, 4));
        float ex = __expf(u - mx);
        float sum = ex;
        sum += __shfl_xor(sum, 1);
        sum += __shfl_xor(sum, 2);
        sum += __shfl_xor(sum, 4);
        outp[n * 8 + k] = ex / sum;
    }
}

extern "C" void kernel_launch(void* const* d_in, const int* in_sizes, int n_in,
                              void* d_out, int out_size, void* d_ws, size_t ws_size,
                              hipStream_t stream) {
    const float* x = (const float*)d_in[0];
    const int* edge = (const int*)d_in[1];   // int64 inputs arrive as int32
    const int* src = edge;
    const int* dst = edge + E;
    const float* c1_Wl = (const float*)d_in[2];
    const float* c1_bl = (const float*)d_in[3];
    const float* c1_Wr = (const float*)d_in[4];
    const float* c2_Wl = (const float*)d_in[5];
    const float* c2_bl = (const float*)d_in[6];
    const float* c2_Wr = (const float*)d_in[7];
    const float* fc1_W = (const float*)d_in[8];
    const float* fc1_b = (const float*)d_in[9];
    const float* fc2_W = (const float*)d_in[10];
    const float* fc2_b = (const float*)d_in[11];
    float* out = (float*)d_out;

    // workspace layout (bytes):
    //   pos  : E ints (20MB)  -- dead after fill, region reused as hA
    //   col  : E ints (20MB)
    //   off  : N+1 ints
    //   cnt  : N ints
    //   bsum : 1024 ints ; bpre : 1024 ints
    //   hB   : N*F floats (12.8MB)
    char* w = (char*)d_ws;
    int* pos = (int*)w;                              w += (size_t)E * 4;
    int* col = (int*)w;                              w += (size_t)E * 4;
    int* off = (int*)w;                              w += (size_t)(N + 1) * 4;
    int* cnt = (int*)w;                              w += (size_t)N * 4;
    int* bsum = (int*)w;                             w += 1024 * 4;
    int* bpre = (int*)w;                             w += 1024 * 4;
    float* hB = (float*)w;                           w += (size_t)N * F * 4;
    float* hA = (float*)pos;                         // aliases pos (dead after fill)

    const int TB = 256;
    const int NB_SCAN = (N + 255) / 256;             // 782
    const int nblk_nodes = N / 16;                   // 12500

    // ---- CSR build (once per call; graph is layer-invariant) ----
    hipMemsetAsync(cnt, 0, (size_t)N * 4, stream);
    degpos_kernel<<<2048, TB, 0, stream>>>(dst, cnt, pos);
    scanA_kernel<<<NB_SCAN, 256, 0, stream>>>(cnt, bsum);
    scanB_kernel<<<1, 1024, 0, stream>>>(bsum, bpre, NB_SCAN);
    scanC_kernel<<<NB_SCAN, 256, 0, stream>>>(cnt, bpre, off);
    fill_kernel<<<2048, TB, 0, stream>>>(src, dst, pos, off, col);

    // ---- 4 fused layers (ping-pong hA/hB; layer reads are cross-node, so no in-place) ----
    layer_kernel<<<nblk_nodes, TB, 0, stream>>>(x, hA, off, col,
        c1_Wl, c1_bl, c1_Wr, nullptr, nullptr, 0, nullptr);
    layer_kernel<<<nblk_nodes, TB, 0, stream>>>(hA, hB, off, col,
        c1_Wl + F * F, c1_bl + F, c1_Wr + F * F, fc1_W, fc1_b, 1, nullptr);
    layer_kernel<<<nblk_nodes, TB, 0, stream>>>(hB, hA, off, col,
        c2_Wl, c2_bl, c2_Wr, nullptr, nullptr, 0, nullptr);
    layer_kernel<<<nblk_nodes, TB, 0, stream>>>(hA, nullptr, off, col,
        c2_Wl + F * F, c2_bl + F, c2_Wr + F * F, fc2_W, fc2_b, 2, out);
}

// Round 4
// 1063.692 us; speedup vs baseline: 2.1242x; 2.1242x over previous
//
#include <hip/hip_runtime.h>

constexpr int N = 200000;
constexpr int E = 5000000;
constexpr int F = 16;
constexpr int CAP = 2048;   // LDS col staging per block: 16 nodes, E[sum deg]=400, 80 sigma margin

// ---- degree count ----
__global__ void deg_kernel(const int* __restrict__ dst, int* __restrict__ cnt) {
    int stride = gridDim.x * blockDim.x;
    for (int e = blockIdx.x * blockDim.x + threadIdx.x; e < E; e += stride)
        atomicAdd(&cnt[dst[e]], 1);
}

// ---- exclusive scan of cnt -> off (and a second copy cur for the fill pass) ----
__global__ void scanA_kernel(const int* __restrict__ cnt, int* __restrict__ bsum) {
    __shared__ int sm[256];
    int n = blockIdx.x * 256 + threadIdx.x;
    int v = (n < N) ? cnt[n] : 0;
    sm[threadIdx.x] = v; __syncthreads();
    for (int s = 128; s > 0; s >>= 1) {
        if (threadIdx.x < s) sm[threadIdx.x] += sm[threadIdx.x + s];
        __syncthreads();
    }
    if (threadIdx.x == 0) bsum[blockIdx.x] = sm[0];
}

__global__ void scanB_kernel(const int* __restrict__ bsum, int* __restrict__ bpre, int nb) {
    __shared__ int sm[1024];
    int i = threadIdx.x;
    int v = (i < nb) ? bsum[i] : 0;
    sm[i] = v; __syncthreads();
    for (int s = 1; s < 1024; s <<= 1) {
        int t = (i >= s) ? sm[i - s] : 0;
        __syncthreads();
        sm[i] += t;
        __syncthreads();
    }
    if (i < nb) bpre[i] = sm[i] - v;   // exclusive
}

__global__ void scanC_kernel(const int* __restrict__ cnt, const int* __restrict__ bpre,
                             int* __restrict__ off, int* __restrict__ cur) {
    __shared__ int sm[256];
    int n = blockIdx.x * 256 + threadIdx.x;
    int v = (n < N) ? cnt[n] : 0;
    sm[threadIdx.x] = v; __syncthreads();
    for (int s = 1; s < 256; s <<= 1) {
        int t = (threadIdx.x >= s) ? sm[threadIdx.x - s] : 0;
        __syncthreads();
        sm[threadIdx.x] += t;
        __syncthreads();
    }
    int exc = bpre[blockIdx.x] + sm[threadIdx.x] - v;
    if (n < N) { off[n] = exc; cur[n] = exc; }
    if (n == N - 1) off[N] = exc + v;
}

// ---- fill CSR cols: atomic-bump slot allocation (order within a node is irrelevant for sum) ----
__global__ void fill_kernel(const int* __restrict__ src, const int* __restrict__ dst,
                            int* __restrict__ cur, int* __restrict__ col) {
    int stride = gridDim.x * blockDim.x;
    for (int e = blockIdx.x * blockDim.x + threadIdx.x; e < E; e += stride) {
        int idx = atomicAdd(&cur[dst[e]], 1);
        __builtin_nontemporal_store(src[e], &col[idx]);
    }
}

// ---- fused gather + SAGE update (+optional fc1 / fc2+softmax) ----
// block = 256 threads = 16 nodes x 16 feature-lanes; N/16 = 12500 blocks exactly
__global__ __launch_bounds__(256) void layer_kernel(
    const float* __restrict__ hin, float* __restrict__ hout,
    const int* __restrict__ off, const int* __restrict__ col,
    const float* __restrict__ Wl, const float* __restrict__ bl,
    const float* __restrict__ Wr,
    const float* __restrict__ fcW, const float* __restrict__ fcb,
    int mode,                 // 0 = plain, 1 = +fc1+relu, 2 = final (slice8+fc2+relu+softmax)
    float* __restrict__ outp) {
    __shared__ int cols[CAP];
    __shared__ float Mt[16][17], Xt[16][17];
    const int tid = threadIdx.x;
    const int nb = blockIdx.x * 16;
    const int base = off[nb];
    const int tot = off[nb + 16] - base;
    const int stot = min(tot, CAP);
    for (int j = tid; j < stot; j += 256)           // coalesced stage of this block's col range
        cols[j] = col[base + j];
    __syncthreads();

    const int ty = tid >> 4;
    const int k  = tid & 15;
    const int n  = nb + ty;
    const int o0 = off[n] - base, o1 = off[n + 1] - base;

    // unroll x8 with independent accumulators -> 8 outstanding gathers per group
    float a0 = 0, a1 = 0, a2 = 0, a3 = 0, a4 = 0, a5 = 0, a6 = 0, a7 = 0;
    const int lim = min(o1, CAP);
    int j = o0;
    for (; j + 8 <= lim; j += 8) {
        int c0 = cols[j],     c1 = cols[j + 1], c2 = cols[j + 2], c3 = cols[j + 3];
        int c4 = cols[j + 4], c5 = cols[j + 5], c6 = cols[j + 6], c7 = cols[j + 7];
        a0 += hin[c0 * F + k]; a1 += hin[c1 * F + k];
        a2 += hin[c2 * F + k]; a3 += hin[c3 * F + k];
        a4 += hin[c4 * F + k]; a5 += hin[c5 * F + k];
        a6 += hin[c6 * F + k]; a7 += hin[c7 * F + k];
    }
    for (; j < lim; j++) a0 += hin[cols[j] * F + k];
    for (; j < o1; j++)  a0 += hin[col[base + j] * F + k];   // LDS-overflow path (never in practice)
    float acc = ((a0 + a1) + (a2 + a3)) + ((a4 + a5) + (a6 + a7));

    const float inv = 1.f / fmaxf((float)(o1 - o0), 1.f);
    Mt[ty][k] = acc * inv;
    Xt[ty][k] = hin[n * F + k];
    __syncthreads();

    float a = bl[k];
#pragma unroll
    for (int kk = 0; kk < F; kk++)
        a = fmaf(Mt[ty][kk], Wl[k * F + kk], fmaf(Xt[ty][kk], Wr[k * F + kk], a));
    float o = fmaxf(a, 0.f);   // relu follows every SAGE layer in this graph

    if (mode == 0) { hout[n * F + k] = o; return; }

    __syncthreads();
    Mt[ty][k] = o;
    __syncthreads();

    if (mode == 1) {
        float a2f = fcb[k];
#pragma unroll
        for (int kk = 0; kk < F; kk++) a2f = fmaf(Mt[ty][kk], fcW[k * F + kk], a2f);
        hout[n * F + k] = fmaxf(a2f, 0.f);
        return;
    }

    // final: slice [:, :8] -> fc2 (8x8) -> relu -> softmax over 8
    if (k < 8) {
        float a2f = fcb[k];
#pragma unroll
        for (int kk = 0; kk < 8; kk++) a2f = fmaf(Mt[ty][kk], fcW[k * 8 + kk], a2f);
        float u = fmaxf(a2f, 0.f);
        float mx = u;
        mx = fmaxf(mx, __shfl_xor(mx, 1));
        mx = fmaxf(mx, __shfl_xor(mx, 2));
        mx = fmaxf(mx, __shfl_xor(mx, 4));
        float ex = __expf(u - mx);
        float sum = ex;
        sum += __shfl_xor(sum, 1);
        sum += __shfl_xor(sum, 2);
        sum += __shfl_xor(sum, 4);
        outp[n * 8 + k] = ex / sum;
    }
}

extern "C" void kernel_launch(void* const* d_in, const int* in_sizes, int n_in,
                              void* d_out, int out_size, void* d_ws, size_t ws_size,
                              hipStream_t stream) {
    const float* x = (const float*)d_in[0];
    const int* edge = (const int*)d_in[1];   // int64 inputs arrive as int32
    const int* src = edge;
    const int* dst = edge + E;
    const float* c1_Wl = (const float*)d_in[2];
    const float* c1_bl = (const float*)d_in[3];
    const float* c1_Wr = (const float*)d_in[4];
    const float* c2_Wl = (const float*)d_in[5];
    const float* c2_bl = (const float*)d_in[6];
    const float* c2_Wr = (const float*)d_in[7];
    const float* fc1_W = (const float*)d_in[8];
    const float* fc1_b = (const float*)d_in[9];
    const float* fc2_W = (const float*)d_in[10];
    const float* fc2_b = (const float*)d_in[11];
    float* out = (float*)d_out;

    // workspace layout
    char* w = (char*)d_ws;
    int* col  = (int*)w;   w += (size_t)E * 4;        // 20 MB
    int* off  = (int*)w;   w += (size_t)(N + 1) * 4;
    int* cur  = (int*)w;   w += (size_t)N * 4;
    int* cnt  = (int*)w;   w += (size_t)N * 4;
    int* bsum = (int*)w;   w += 1024 * 4;
    int* bpre = (int*)w;   w += 1024 * 4;
    float* hA = (float*)w; w += (size_t)N * F * 4;    // 12.8 MB
    float* hB = (float*)w; w += (size_t)N * F * 4;    // 12.8 MB

    const int TB = 256;
    const int NB_SCAN = (N + 255) / 256;              // 782
    const int nblk_nodes = N / 16;                    // 12500

    // ---- CSR build (once per call; graph is layer-invariant) ----
    hipMemsetAsync(cnt, 0, (size_t)N * 4, stream);
    deg_kernel<<<2048, TB, 0, stream>>>(dst, cnt);
    scanA_kernel<<<NB_SCAN, 256, 0, stream>>>(cnt, bsum);
    scanB_kernel<<<1, 1024, 0, stream>>>(bsum, bpre, NB_SCAN);
    scanC_kernel<<<NB_SCAN, 256, 0, stream>>>(cnt, bpre, off, cur);
    fill_kernel<<<2048, TB, 0, stream>>>(src, dst, cur, col);

    // ---- 4 fused layers (ping-pong hA/hB) ----
    layer_kernel<<<nblk_nodes, TB, 0, stream>>>(x, hA, off, col,
        c1_Wl, c1_bl, c1_Wr, nullptr, nullptr, 0, nullptr);
    layer_kernel<<<nblk_nodes, TB, 0, stream>>>(hA, hB, off, col,
        c1_Wl + F * F, c1_bl + F, c1_Wr + F * F, fc1_W, fc1_b, 1, nullptr);
    layer_kernel<<<nblk_nodes, TB, 0, stream>>>(hB, hA, off, col,
        c2_Wl, c2_bl, c2_Wr, nullptr, nullptr, 0, nullptr);
    layer_kernel<<<nblk_nodes, TB, 0, stream>>>(hA, nullptr, off, col,
        c2_Wl + F * F, c2_bl + F, c2_Wr + F * F, fc2_W, fc2_b, 2, out);
}

// Round 5
// 648.832 us; speedup vs baseline: 3.4824x; 1.6394x over previous
//
#include <hip/hip_runtime.h>

constexpr int N = 200000;
constexpr int E = 5000000;
constexpr int F = 16;
constexpr int CAP = 2048;        // LDS col staging per layer block
constexpr int BUCKB = 10;        // bucket = dst >> 10 (1024 nodes/bucket)
constexpr int NBKT = (N + 1023) >> 10;   // 196
constexpr int NB_CH = 512;       // chunk blocks for hist/scatter

// ---- 1: per-(bucket, block) histogram of dst ----
__global__ __launch_bounds__(256) void hist_kernel(const int* __restrict__ dst,
                                                   int* __restrict__ hist) {
    __shared__ int h[NBKT];
    for (int i = threadIdx.x; i < NBKT; i += 256) h[i] = 0;
    __syncthreads();
    const int chunk = (E + NB_CH - 1) / NB_CH;
    const int lo = blockIdx.x * chunk, hi = min(E, lo + chunk);
    for (int e = lo + threadIdx.x; e < hi; e += 256)
        atomicAdd(&h[dst[e] >> BUCKB], 1);
    __syncthreads();
    for (int i = threadIdx.x; i < NBKT; i += 256)
        hist[i * NB_CH + blockIdx.x] = h[i];   // bucket-major
}

// ---- 2: exclusive scan of hist (NBKT*NB_CH ints) in place; extract bucket starts ----
__global__ __launch_bounds__(1024) void scan_hist_kernel(int* __restrict__ hist,
                                                         int* __restrict__ bstart) {
    __shared__ int sm[1024];
    const int M = NBKT * NB_CH;
    const int per = (M + 1023) / 1024;
    const int t = threadIdx.x;
    const int lo = t * per, hi = min(M, lo + per);
    int s = 0;
    for (int i = lo; i < hi; i++) s += hist[i];
    sm[t] = s; __syncthreads();
    for (int st = 1; st < 1024; st <<= 1) {
        int v = (t >= st) ? sm[t - st] : 0;
        __syncthreads();
        sm[t] += v;
        __syncthreads();
    }
    int run = sm[t] - s;                      // exclusive base for this thread's range
    for (int i = lo; i < hi; i++) { int v = hist[i]; hist[i] = run; run += v; }
    __syncthreads();                          // global writes visible block-wide
    if (t <= NBKT) bstart[t] = (t < NBKT) ? hist[t * NB_CH] : E;
}

// ---- 3: scatter packed (dst,src) pairs into bucket-major order ----
__global__ __launch_bounds__(256) void bucket_scatter_kernel(const int* __restrict__ src,
                                                             const int* __restrict__ dst,
                                                             const int* __restrict__ hist,
                                                             long long* __restrict__ pairs) {
    __shared__ int cur[NBKT];
    for (int i = threadIdx.x; i < NBKT; i += 256) cur[i] = hist[i * NB_CH + blockIdx.x];
    __syncthreads();
    const int chunk = (E + NB_CH - 1) / NB_CH;
    const int lo = blockIdx.x * chunk, hi = min(E, lo + chunk);
    for (int e = lo + threadIdx.x; e < hi; e += 256) {
        int d = dst[e];
        int p = atomicAdd(&cur[d >> BUCKB], 1);
        long long pk = ((long long)d << 32) | (unsigned)src[e];
        __builtin_nontemporal_store(pk, &pairs[p]);
    }
}

// ---- 4: per-bucket exact CSR: off (replaces deg+scan) + bucket-local col scatter ----
__global__ __launch_bounds__(256) void build_csr_kernel(const long long* __restrict__ pairs,
                                                        const int* __restrict__ bstart,
                                                        int* __restrict__ off,
                                                        int* __restrict__ col) {
    __shared__ int cnt[1024];
    __shared__ int sm[256];
    const int b = blockIdx.x;
    const int p0 = bstart[b], p1 = bstart[b + 1];
    const int nodeBase = b << BUCKB;
    const int t = threadIdx.x;
    for (int i = t; i < 1024; i += 256) cnt[i] = 0;
    __syncthreads();
    for (int j = p0 + t; j < p1; j += 256)
        atomicAdd(&cnt[(int)(pairs[j] >> 32) - nodeBase], 1);
    __syncthreads();
    // exclusive scan of cnt[1024] with 256 threads (4 elems each)
    int c0 = cnt[4 * t], c1 = cnt[4 * t + 1], c2 = cnt[4 * t + 2], c3 = cnt[4 * t + 3];
    int s = c0 + c1 + c2 + c3;
    sm[t] = s; __syncthreads();
    for (int st = 1; st < 256; st <<= 1) {
        int v = (t >= st) ? sm[t - st] : 0;
        __syncthreads();
        sm[t] += v;
        __syncthreads();
    }
    const int abs0 = p0 + sm[t] - s;
    cnt[4 * t] = abs0;
    cnt[4 * t + 1] = abs0 + c0;
    cnt[4 * t + 2] = abs0 + c0 + c1;
    cnt[4 * t + 3] = abs0 + c0 + c1 + c2;
    const int n0 = nodeBase + 4 * t;
#pragma unroll
    for (int q = 0; q < 4; q++)
        if (n0 + q < N) off[n0 + q] = cnt[4 * t + q];
    if (b == gridDim.x - 1 && t == 255) off[N] = p1;
    __syncthreads();
    for (int j = p0 + t; j < p1; j += 256) {
        long long pk = pairs[j];
        int d = (int)(pk >> 32);
        int p = atomicAdd(&cnt[d - nodeBase], 1);
        col[p] = (int)(pk & 0xffffffffLL);
    }
}

// ---- fused gather + SAGE update (+optional fc1 / fc2+softmax) ----
// block = 256 threads = 16 nodes x 16 feature-lanes; N/16 = 12500 blocks exactly
__global__ __launch_bounds__(256) void layer_kernel(
    const float* __restrict__ hin, float* __restrict__ hout,
    const int* __restrict__ off, const int* __restrict__ col,
    const float* __restrict__ Wl, const float* __restrict__ bl,
    const float* __restrict__ Wr,
    const float* __restrict__ fcW, const float* __restrict__ fcb,
    int mode,                 // 0 = plain, 1 = +fc1+relu, 2 = final (slice8+fc2+relu+softmax)
    float* __restrict__ outp) {
    __shared__ int cols[CAP];
    __shared__ float Mt[16][17], Xt[16][17];
    const int tid = threadIdx.x;
    const int nb = blockIdx.x * 16;
    const int base = off[nb];
    const int tot = off[nb + 16] - base;
    const int stot = min(tot, CAP);
    for (int j = tid; j < stot; j += 256)           // coalesced stage of this block's col range
        cols[j] = col[base + j];
    __syncthreads();

    const int ty = tid >> 4;
    const int k  = tid & 15;
    const int n  = nb + ty;
    const int o0 = off[n] - base, o1 = off[n + 1] - base;

    // unroll x8 with independent accumulators -> 8 outstanding gathers per group
    float a0 = 0, a1 = 0, a2 = 0, a3 = 0, a4 = 0, a5 = 0, a6 = 0, a7 = 0;
    const int lim = min(o1, CAP);
    int j = o0;
    for (; j + 8 <= lim; j += 8) {
        int c0 = cols[j],     c1 = cols[j + 1], c2 = cols[j + 2], c3 = cols[j + 3];
        int c4 = cols[j + 4], c5 = cols[j + 5], c6 = cols[j + 6], c7 = cols[j + 7];
        a0 += hin[c0 * F + k]; a1 += hin[c1 * F + k];
        a2 += hin[c2 * F + k]; a3 += hin[c3 * F + k];
        a4 += hin[c4 * F + k]; a5 += hin[c5 * F + k];
        a6 += hin[c6 * F + k]; a7 += hin[c7 * F + k];
    }
    for (; j < lim; j++) a0 += hin[cols[j] * F + k];
    for (; j < o1; j++)  a0 += hin[col[base + j] * F + k];   // LDS-overflow path (never in practice)
    float acc = ((a0 + a1) + (a2 + a3)) + ((a4 + a5) + (a6 + a7));

    const float inv = 1.f / fmaxf((float)(o1 - o0), 1.f);
    Mt[ty][k] = acc * inv;
    Xt[ty][k] = hin[n * F + k];
    __syncthreads();

    float a = bl[k];
#pragma unroll
    for (int kk = 0; kk < F; kk++)
        a = fmaf(Mt[ty][kk], Wl[k * F + kk], fmaf(Xt[ty][kk], Wr[k * F + kk], a));
    float o = fmaxf(a, 0.f);   // relu follows every SAGE layer in this graph

    if (mode == 0) { hout[n * F + k] = o; return; }

    __syncthreads();
    Mt[ty][k] = o;
    __syncthreads();

    if (mode == 1) {
        float a2f = fcb[k];
#pragma unroll
        for (int kk = 0; kk < F; kk++) a2f = fmaf(Mt[ty][kk], fcW[k * F + kk], a2f);
        hout[n * F + k] = fmaxf(a2f, 0.f);
        return;
    }

    // final: slice [:, :8] -> fc2 (8x8) -> relu -> softmax over 8
    if (k < 8) {
        float a2f = fcb[k];
#pragma unroll
        for (int kk = 0; kk < 8; kk++) a2f = fmaf(Mt[ty][kk], fcW[k * 8 + kk], a2f);
        float u = fmaxf(a2f, 0.f);
        float mx = u;
        mx = fmaxf(mx, __shfl_xor(mx, 1));
        mx = fmaxf(mx, __shfl_xor(mx, 2));
        mx = fmaxf(mx, __shfl_xor(mx, 4));
        float ex = __expf(u - mx);
        float sum = ex;
        sum += __shfl_xor(sum, 1);
        sum += __shfl_xor(sum, 2);
        sum += __shfl_xor(sum, 4);
        outp[n * 8 + k] = ex / sum;
    }
}

extern "C" void kernel_launch(void* const* d_in, const int* in_sizes, int n_in,
                              void* d_out, int out_size, void* d_ws, size_t ws_size,
                              hipStream_t stream) {
    const float* x = (const float*)d_in[0];
    const int* edge = (const int*)d_in[1];   // int64 inputs arrive as int32
    const int* src = edge;
    const int* dst = edge + E;
    const float* c1_Wl = (const float*)d_in[2];
    const float* c1_bl = (const float*)d_in[3];
    const float* c1_Wr = (const float*)d_in[4];
    const float* c2_Wl = (const float*)d_in[5];
    const float* c2_bl = (const float*)d_in[6];
    const float* c2_Wr = (const float*)d_in[7];
    const float* fc1_W = (const float*)d_in[8];
    const float* fc1_b = (const float*)d_in[9];
    const float* fc2_W = (const float*)d_in[10];
    const float* fc2_b = (const float*)d_in[11];
    float* out = (float*)d_out;

    // workspace layout:
    //   pairs : E * 8B (40MB)  -- dead after build_csr, reused as hA+hB (25.6MB)
    //   col   : E * 4B (20MB)
    //   off   : (N+1) * 4B
    //   hist  : NBKT*NB_CH * 4B (~400KB)
    //   bstart: (NBKT+1) * 4B
    char* w = (char*)d_ws;
    long long* pairs = (long long*)w;  w += (size_t)E * 8;
    int* col  = (int*)w;               w += (size_t)E * 4;
    int* off  = (int*)w;               w += (size_t)(N + 1) * 4;
    int* hist = (int*)w;               w += (size_t)NBKT * NB_CH * 4;
    int* bstart = (int*)w;             w += (size_t)(NBKT + 1) * 4;
    float* hA = (float*)pairs;                       // aliases pairs (dead after build)
    float* hB = hA + (size_t)N * F;

    const int nblk_nodes = N / 16;                   // 12500

    // ---- CSR build: bucket counting sort; off computed in-bucket (no deg/scan kernels) ----
    hist_kernel<<<NB_CH, 256, 0, stream>>>(dst, hist);
    scan_hist_kernel<<<1, 1024, 0, stream>>>(hist, bstart);
    bucket_scatter_kernel<<<NB_CH, 256, 0, stream>>>(src, dst, hist, pairs);
    build_csr_kernel<<<NBKT, 256, 0, stream>>>(pairs, bstart, off, col);

    // ---- 4 fused layers (ping-pong hA/hB) ----
    layer_kernel<<<nblk_nodes, 256, 0, stream>>>(x, hA, off, col,
        c1_Wl, c1_bl, c1_Wr, nullptr, nullptr, 0, nullptr);
    layer_kernel<<<nblk_nodes, 256, 0, stream>>>(hA, hB, off, col,
        c1_Wl + F * F, c1_bl + F, c1_Wr + F * F, fc1_W, fc1_b, 1, nullptr);
    layer_kernel<<<nblk_nodes, 256, 0, stream>>>(hB, hA, off, col,
        c2_Wl, c2_bl, c2_Wr, nullptr, nullptr, 0, nullptr);
    layer_kernel<<<nblk_nodes, 256, 0, stream>>>(hA, nullptr, off, col,
        c2_Wl + F * F, c2_bl + F, c2_Wr + F * F, fc2_W, fc2_b, 2, out);
}